// Round 9
// baseline (1530.352 us; speedup 1.0000x reference)
//
#include <hip/hip_runtime.h>
#include <hip/hip_bf16.h>
#include <math.h>

// Problem constants
#define BB     256
#define NMEL   80
#define TMEL   800
#define NFR    16          // frames per step
#define TT     50          // decoder steps
#define RNN    1024
#define ENC    256
#define INDIM  1280        // RNN + ENC == MEL_DIM
#define G4     4096        // 4*RNN
#define MROWS  (TT*BB)     // 12800

typedef __attribute__((ext_vector_type(8))) short bf16x8;
typedef __attribute__((ext_vector_type(4))) float f32x4;

#define GAS __attribute__((address_space(1)))
#define LAS __attribute__((address_space(3)))

__device__ __forceinline__ unsigned short f2bf(float f) {
    unsigned int u = __float_as_uint(f);
    u += 0x7FFFu + ((u >> 16) & 1u);     // round-to-nearest-even
    return (unsigned short)(u >> 16);
}
__device__ __forceinline__ float bf2f(unsigned short s) {
    return __uint_as_float(((unsigned int)s) << 16);
}

// ---------------- prep kernels ----------------

__global__ void k_f32_to_bf16(const float* __restrict__ src,
                              unsigned short* __restrict__ dst, int n) {
    for (int i = blockIdx.x * blockDim.x + threadIdx.x; i < n;
         i += gridDim.x * blockDim.x)
        dst[i] = f2bf(src[i]);
}

// W_proj[:, 0:1024] -> bf16, N-permuted: dst row m' = mel*16+fr comes from
// W_proj row m = fr*80+mel. Makes mel-GEMM output contiguous along (t,fr).
__global__ void k_conv_wph(const float* __restrict__ wproj,
                           unsigned short* __restrict__ dst) {
    const int n = INDIM * RNN;
    for (int i = blockIdx.x * blockDim.x + threadIdx.x; i < n;
         i += gridDim.x * blockDim.x) {
        int mp = i >> 10, k = i & 1023;
        int mel = mp >> 4, fr = mp & 15;
        dst[i] = f2bf(wproj[(fr * NMEL + mel) * INDIM + k]);
    }
}

// teacher-forced inputs: frames[t][b][k] = (t==0)?0:target[b][k%80][t*16+k/80]
__global__ void k_frames(const float* __restrict__ target,
                         unsigned short* __restrict__ frames) {
    const int n = TT * BB * INDIM;
    for (int i = blockIdx.x * blockDim.x + threadIdx.x; i < n;
         i += gridDim.x * blockDim.x) {
        int k = i % INDIM;
        int rb = i / INDIM;
        int b = rb & (BB - 1);
        int t = rb >> 8;
        unsigned short v = 0;
        if (t > 0) {
            int mel = k % NMEL, fr = k / NMEL;
            v = f2bf(target[(b * NMEL + mel) * TMEL + t * NFR + fr]);
        }
        frames[i] = v;
    }
}

// ctxproj[b][m'] = b_proj[m] + context[b]·W_proj[m][1024:1280], m'=mel*16+fr,
// m = fr*80+mel (same permutation as k_conv_wph).
__global__ void k_ctxproj(const float* __restrict__ context,
                          const float* __restrict__ wproj,
                          const float* __restrict__ bproj,
                          float* __restrict__ ctx) {
    int i = blockIdx.x * blockDim.x + threadIdx.x;
    if (i >= BB * INDIM) return;
    int mp = i % INDIM, b = i / INDIM;
    int mel = mp >> 4, fr = mp & 15;
    int m = fr * NMEL + mel;
    const float* wr = wproj + (size_t)m * INDIM + RNN;
    const float* cb = context + b * ENC;
    float acc = bproj[m];
    for (int e = 0; e < ENC; ++e) acc += cb[e] * wr[e];
    ctx[(size_t)b * INDIM + mp] = acc;
}

// gatectx[b] = b_gate + context[b]·W_gate[0][1024:1280]
__global__ void k_gatectx(const float* __restrict__ context,
                          const float* __restrict__ wgate,
                          const float* __restrict__ bgate,
                          float* __restrict__ gctx) {
    int b = blockIdx.x * blockDim.x + threadIdx.x;
    if (b >= BB) return;
    float acc = bgate[0];
    const float* cb = context + b * ENC;
    for (int e = 0; e < ENC; ++e) acc += cb[e] * wgate[RNN + e];
    gctx[b] = acc;
}

// ---------------- m97-structure tile GEMM core ----------------
template<int STRIDE, int KDIM>
__device__ __forceinline__ void gemm_core(const unsigned short* __restrict__ A,
                                          const unsigned short* __restrict__ Bw,
                                          int mblk, int nblk,
                                          unsigned short* As, unsigned short* Bs,
                                          f32x4 acc[4][4]) {
    const int tid = threadIdx.x, lane = tid & 63, wid = tid >> 6;
    const int wm = (wid >> 1) * 64, wn = (wid & 1) * 64;
    const int lr = lane & 15, lko = (lane >> 4) * 8;
    const int c0 = wid * 128 + lane;          // call 0 chunk for this lane
    const int c1 = c0 + 64;                   // call 1
    const int r0 = c0 >> 2, o0 = (c0 & 3) * 8;
    const int r1 = c1 >> 2, o1 = (c1 & 3) * 8;
    const unsigned short* a0p = A + (size_t)(mblk + r0) * STRIDE + o0;
    const unsigned short* a1p = A + (size_t)(mblk + r1) * STRIDE + o1;
    const unsigned short* b0p = Bw + (size_t)(nblk + r0) * STRIDE + o0;
    const unsigned short* b1p = Bw + (size_t)(nblk + r1) * STRIDE + o1;
    unsigned short* da0 = As + wid * 1024;          // uniform per wave
    unsigned short* da1 = As + wid * 1024 + 512;
    unsigned short* db0 = Bs + wid * 1024;
    unsigned short* db1 = Bs + wid * 1024 + 512;
    for (int k0 = 0; k0 < KDIM; k0 += 32) {
        __syncthreads();   // previous compute done before LDS overwrite
        __builtin_amdgcn_global_load_lds((const GAS unsigned int*)(a0p + k0),
                                         (LAS unsigned int*)da0, 16, 0, 0);
        __builtin_amdgcn_global_load_lds((const GAS unsigned int*)(a1p + k0),
                                         (LAS unsigned int*)da1, 16, 0, 0);
        __builtin_amdgcn_global_load_lds((const GAS unsigned int*)(b0p + k0),
                                         (LAS unsigned int*)db0, 16, 0, 0);
        __builtin_amdgcn_global_load_lds((const GAS unsigned int*)(b1p + k0),
                                         (LAS unsigned int*)db1, 16, 0, 0);
        __syncthreads();   // compiler drains vmcnt before barrier
        bf16x8 af[4], bfv[4];
        #pragma unroll
        for (int mi = 0; mi < 4; ++mi)
            af[mi] = *(const bf16x8*)(As + (wm + mi * 16 + lr) * 32 + lko);
        #pragma unroll
        for (int ni = 0; ni < 4; ++ni)
            bfv[ni] = *(const bf16x8*)(Bs + (wn + ni * 16 + lr) * 32 + lko);
        #pragma unroll
        for (int mi = 0; mi < 4; ++mi)
            #pragma unroll
            for (int ni = 0; ni < 4; ++ni)
                acc[mi][ni] = __builtin_amdgcn_mfma_f32_16x16x32_bf16(
                    af[mi], bfv[ni], acc[mi][ni], 0, 0, 0);
    }
}

// GEMM 1: xproj = frames @ W_ih^T + b_ih + b_hh (bf16 out). M=12800 N=4096 K=1280
__global__ __launch_bounds__(256) void k_gemm_xproj(
    const unsigned short* __restrict__ A,   // [12800][1280]
    const unsigned short* __restrict__ Bw,  // [4096][1280]
    const float* __restrict__ b_ih, const float* __restrict__ b_hh,
    unsigned short* __restrict__ Cout)      // [12800][4096]
{
    __shared__ unsigned short As[4096], Bs[4096];
    f32x4 acc[4][4] = {};
    const int mblk = blockIdx.y * 128, nblk = blockIdx.x * 128;
    gemm_core<INDIM, INDIM>(A, Bw, mblk, nblk, As, Bs, acc);
    const int lane = threadIdx.x & 63, wid = threadIdx.x >> 6;
    const int wm = (wid >> 1) * 64, wn = (wid & 1) * 64, lr = lane & 15;
    #pragma unroll
    for (int ni = 0; ni < 4; ++ni) {
        const int col = nblk + wn + ni * 16 + lr;
        const float bias = b_ih[col] + b_hh[col];
        #pragma unroll
        for (int mi = 0; mi < 4; ++mi) {
            const int row0 = mblk + wm + mi * 16 + (lane >> 4) * 4;
            #pragma unroll
            for (int r = 0; r < 4; ++r)
                Cout[(size_t)(row0 + r) * G4 + col] = f2bf(acc[mi][ni][r] + bias);
        }
    }
}

// GEMM 2: mel = h_all[1:] @ Wp'^T + ctxproj', coalesced scatter via LDS
// transpose. M=12800, N=1280 (permuted col' = mel*16+fr), K=1024.
__global__ __launch_bounds__(256) void k_gemm_mel(
    const unsigned short* __restrict__ A,   // [12800][1024]
    const unsigned short* __restrict__ Bw,  // Wp' [1280][1024] (permuted)
    const float* __restrict__ ctxproj,      // [256][1280] (permuted)
    float* __restrict__ out0)               // [256][80][800]
{
    __shared__ unsigned short As[4096], Bs[4096];
    __shared__ float txp[4][16][20];        // per-wave transpose; 20: align+banks
    f32x4 acc[4][4] = {};
    const int mblk = blockIdx.y * 128, nblk = blockIdx.x * 128;
    gemm_core<RNN, RNN>(A, Bw, mblk, nblk, As, Bs, acc);
    const int lane = threadIdx.x & 63, wid = threadIdx.x >> 6;
    const int wm = (wid >> 1) * 64, wn = (wid & 1) * 64, lr = lane & 15;
    const int rbase = (lane >> 4) * 4;
    const int rowl = lane & 15, fq = lane >> 4;   // readback roles
    #pragma unroll
    for (int mi = 0; mi < 4; ++mi) {
        const int row0 = mblk + wm + mi * 16;     // 16 rows: same t, b0..b0+15
        const int t = row0 >> 8, b0 = row0 & 255;
        #pragma unroll
        for (int ni = 0; ni < 4; ++ni) {
            const int colbase = nblk + wn + ni * 16;  // one mel, fr 0..15
            const int mel = colbase >> 4;
            __syncthreads();                      // txp free for reuse
            #pragma unroll
            for (int r = 0; r < 4; ++r)
                txp[wid][rbase + r][lr] = acc[mi][ni][r];
            __syncthreads();                      // transpose visible
            const int bL = b0 + rowl;
            f32x4 v = *(const f32x4*)&txp[wid][rowl][fq * 4];
            f32x4 cx = *(const f32x4*)(ctxproj + (size_t)bL * INDIM +
                                       mel * 16 + fq * 4);
            *(f32x4*)(out0 + (size_t)(bL * NMEL + mel) * TMEL +
                      t * NFR + fq * 4) = v + cx;
        }
    }
}

// ---------------- persistent recurrence kernel (v8) ----------------
// LSTM recurrence is independent per batch row -> bands = batch groups with
// ZERO cross-band coupling. 512 WGs x 512 thr, 2 WG/CU (LDS ~67KB): the
// co-resident partner WG (independent band) computes while this one spins.
// WG (by = bid>>6, bx = bid&63): rows [by*32,+32), cols [bx*16,+16) x 4 gates.
// 8 waves: g = w&3, mh = w>>2 (16-row half). BK=64, 4-deep counted-vmcnt
// pipeline (all staging global_load_lds; no compiler drains). Natural XCD
// mapping keeps per-XCD Whh at 1MB (L2-resident — the v6-measured regime).
// Band sync: per-WG flag (release store, no atomic contention) + wave-0
// lane-parallel poll of all 64 band flags (one load round-trip per poll).
__global__ __launch_bounds__(512, 4) void k_recur(
    const unsigned short* __restrict__ Whh,    // [4096][1024] bf16
    const unsigned short* __restrict__ xproj,  // [50][256][4096] bf16
    unsigned short* __restrict__ h_all,        // [51][256][1024] bf16
    unsigned int* __restrict__ flags)          // [8][64] zeroed per call
{
    __shared__ unsigned short Abuf[4][2048];   // h 32r x 64k per buf (4KB x4)
    __shared__ unsigned short Bbuf[4][4096];   // Whh 64vr x 64k per buf (8KB x4)
    __shared__ unsigned short xg[2][2048];     // xproj tile [4][32][16] dbuf
    __shared__ float gates[4][32][17];         // 8.7KB, +1 pad
    __shared__ float cst[32][16];              // 2KB cell state (persistent)
    const int tid = threadIdx.x, lane = tid & 63, w = tid >> 6;
    const int g = w & 3, mh = w >> 2;
    const int by = blockIdx.x >> 6, bx = blockIdx.x & 63;
    const int m0 = by * 32, n0 = bx * 16;
    const int lr = lane & 15, q = lane >> 4;
    const int sx = lr & 7;

    // B staging: 512 chunks (1/thread): vr = tid>>3 (gate vr>>4, col vr&15),
    // 16B-sub = tid&7; XOR-swizzled global source (both-sides rule).
    const int vrB = tid >> 3, sB = tid & 7;
    const unsigned short* bsrc = Whh +
        (size_t)((vrB >> 4) * RNN + n0 + (vrB & 15)) * RNN + ((sB ^ (vrB & 7)) * 8);
    // A staging: 256 chunks, waves 0-3 (tid<256): row = tid>>3, sub = tid&7
    const int rA = tid >> 3, sA = tid & 7;
    const size_t a_off = (size_t)(m0 + (rA & 31)) * RNN + ((sA ^ (rA & 7)) * 8);
    // xg staging (tid<256): chunk tid -> g = tid>>6, row = (tid>>1)&31, half
    const size_t xg_off = (size_t)(m0 + ((tid >> 1) & 31)) * G4 +
                          (tid >> 6) * RNN + n0 + (tid & 1) * 8;

    cst[tid >> 4][tid & 15] = 0.f;             // 512 entries, 1/thread

#define STAGE(buf, k0) do {                                                    \
    __builtin_amdgcn_global_load_lds((const GAS unsigned int*)(bsrc + (k0)),   \
        (LAS unsigned int*)&Bbuf[buf][w * 512], 16, 0, 0);                     \
    if (w < 4)                                                                 \
        __builtin_amdgcn_global_load_lds((const GAS unsigned int*)(asrc + (k0)),\
            (LAS unsigned int*)&Abuf[buf][w * 512], 16, 0, 0); } while (0)

    // xg stage for step 0
    if (w < 4)
        __builtin_amdgcn_global_load_lds((const GAS unsigned int*)(xproj + xg_off),
            (LAS unsigned int*)&xg[0][w * 512], 16, 0, 0);

    for (int tt = 0; tt < TT; ++tt) {
        const unsigned short* asrc = h_all + (size_t)tt * BB * RNN + a_off;
        unsigned short* hn = h_all + (size_t)(tt + 1) * BB * RNN;

        STAGE(0, 0); STAGE(1, 64); STAGE(2, 128);   // 3-ahead prologue

        f32x4 acc = {};
        #pragma unroll
        for (int it = 0; it < 16; ++it) {
            if (it <= 12) STAGE((it + 3) & 3, (it + 3) * 64);
            // wait own stage(it); newer stages (only) stay in flight
            if (w < 4) {
                if (it <= 12)      asm volatile("s_waitcnt vmcnt(6)" ::: "memory");
                else if (it == 13) asm volatile("s_waitcnt vmcnt(4)" ::: "memory");
                else if (it == 14) asm volatile("s_waitcnt vmcnt(2)" ::: "memory");
                else               asm volatile("s_waitcnt vmcnt(0)" ::: "memory");
            } else {
                if (it <= 12)      asm volatile("s_waitcnt vmcnt(3)" ::: "memory");
                else if (it == 13) asm volatile("s_waitcnt vmcnt(2)" ::: "memory");
                else if (it == 14) asm volatile("s_waitcnt vmcnt(1)" ::: "memory");
                else               asm volatile("s_waitcnt vmcnt(0)" ::: "memory");
            }
            asm volatile("s_barrier" ::: "memory");
            __builtin_amdgcn_sched_barrier(0);
            const unsigned short* Ab = Abuf[it & 3];
            const unsigned short* Bb = Bbuf[it & 3];
            #pragma unroll
            for (int ks = 0; ks < 2; ++ks) {
                const int sub = ks * 4 + q;
                bf16x8 av = *(const bf16x8*)(Ab + (mh * 16 + lr) * 64 + ((sub ^ sx) * 8));
                bf16x8 bv = *(const bf16x8*)(Bb + (g * 16 + lr) * 64 + ((sub ^ sx) * 8));
                acc = __builtin_amdgcn_mfma_f32_16x16x32_bf16(av, bv, acc, 0, 0, 0);
            }
            asm volatile("s_waitcnt lgkmcnt(0)" ::: "memory");
            __builtin_amdgcn_sched_barrier(0);
            asm volatile("s_barrier" ::: "memory");
        }

        // epilogue: gates = acc + xg (wave-exclusive (g, mh) rows)
        #pragma unroll
        for (int r = 0; r < 4; ++r) {
            const int row = mh * 16 + q * 4 + r;
            gates[g][row][lr] = acc[r] +
                bf2f(xg[tt & 1][(g * 32 + row) * 16 + lr]);
        }
        asm volatile("s_waitcnt lgkmcnt(0)" ::: "memory");
        asm volatile("s_barrier" ::: "memory");

        // LSTM tail: 512 threads, 1 element each (32x16)
        {
            const int row = tid >> 4, col = tid & 15;
            const float xi = gates[0][row][col];
            const float xf = gates[1][row][col];
            const float xgt = gates[2][row][col];
            const float xo = gates[3][row][col];
            const float si = 1.f / (1.f + expf(-xi));
            const float sf = 1.f / (1.f + expf(-xf));
            const float so = 1.f / (1.f + expf(-xo));
            const float cp = cst[row][col];
            const float cn = sf * cp + si * tanhf(xgt);
            const float hnv = so * tanhf(cn);
            cst[row][col] = cn;
            hn[(size_t)(m0 + row) * RNN + n0 + col] = f2bf(hnv);
        }

        if (tt < TT - 1) {
            // prefetch next step's xg; its HBM latency hides under the barrier
            if (w < 4)
                __builtin_amdgcn_global_load_lds(
                    (const GAS unsigned int*)(xproj + (size_t)(tt + 1) * BB * G4 + xg_off),
                    (LAS unsigned int*)&xg[(tt + 1) & 1][w * 512], 16, 0, 0);
            // retire h stores (older); xg may stay in flight
            if (w < 4) asm volatile("s_waitcnt vmcnt(1)" ::: "memory");
            else       asm volatile("s_waitcnt vmcnt(0)" ::: "memory");
            asm volatile("s_barrier" ::: "memory");
            if (tid == 0)
                __hip_atomic_store(&flags[(by << 6) + bx], (unsigned)(tt + 1),
                                   __ATOMIC_RELEASE, __HIP_MEMORY_SCOPE_AGENT);
            if (w == 0) {
                const unsigned tgt = (unsigned)(tt + 1);
                for (int p = 0; p < (1 << 22); ++p) {   // bounded: no hang
                    unsigned v = __hip_atomic_load(&flags[(by << 6) + lane],
                                    __ATOMIC_RELAXED, __HIP_MEMORY_SCOPE_AGENT);
                    if (__all((int)(v >= tgt))) break;
                    __builtin_amdgcn_s_sleep(8);
                }
            }
            asm volatile("s_barrier" ::: "memory");
            __builtin_amdgcn_sched_barrier(0);
        }
    }
#undef STAGE
}

// gate[b*50+t] = gatectx[b] + h_all[t+1][b]·w_gate[0:1024] ; one wave per row
__global__ void k_gate(const unsigned short* __restrict__ h,  // [12800][1024]
                       const float* __restrict__ wgate,
                       const float* __restrict__ gctx,
                       float* __restrict__ out1) {
    const int gw = (blockIdx.x * blockDim.x + threadIdx.x) >> 6;
    const int lane = threadIdx.x & 63;
    if (gw >= MROWS) return;
    const unsigned short* hr = h + (size_t)gw * RNN + lane * 16;
    const float* wr = wgate + lane * 16;
    float acc = 0.f;
    #pragma unroll
    for (int j = 0; j < 16; ++j) acc += bf2f(hr[j]) * wr[j];
    for (int off = 32; off; off >>= 1) acc += __shfl_down(acc, off);
    if (lane == 0) {
        const int t = gw >> 8, b = gw & 255;
        out1[b * TT + t] = acc + gctx[b];
    }
}

// ---------------- workspace layout (all offsets 1KB-aligned) ----------------
static const size_t OFF_WIH   = 0;                                    // 10.5 MB
static const size_t OFF_WHH   = OFF_WIH   + (size_t)G4 * INDIM * 2;   // 8 MB
static const size_t OFF_WPH   = OFF_WHH   + (size_t)G4 * RNN * 2;     // 2.6 MB
static const size_t OFF_FRM   = OFF_WPH   + (size_t)INDIM * RNN * 2;  // 32.8 MB
static const size_t OFF_XPROJ = OFF_FRM   + (size_t)MROWS * INDIM * 2;// 104.9 MB
static const size_t OFF_HALL  = OFF_XPROJ + (size_t)MROWS * G4 * 2;   // 26.7 MB
static const size_t OFF_BAR   = OFF_HALL  + (size_t)(TT + 1) * BB * RNN * 2;
static const size_t OFF_CTX   = OFF_BAR   + 4096;
static const size_t OFF_GCTX  = OFF_CTX   + (size_t)BB * INDIM * 4;

extern "C" void kernel_launch(void* const* d_in, const int* in_sizes, int n_in,
                              void* d_out, int out_size, void* d_ws, size_t ws_size,
                              hipStream_t stream) {
    const float* context = (const float*)d_in[0];
    const float* target  = (const float*)d_in[1];
    const float* W_ih    = (const float*)d_in[2];
    const float* b_ih    = (const float*)d_in[3];
    const float* W_hh    = (const float*)d_in[4];
    const float* b_hh    = (const float*)d_in[5];
    const float* W_proj  = (const float*)d_in[6];
    const float* b_proj  = (const float*)d_in[7];
    const float* W_gate  = (const float*)d_in[8];
    const float* b_gate  = (const float*)d_in[9];
    float* out = (float*)d_out;
    char* ws = (char*)d_ws;

    unsigned short* wih_bf  = (unsigned short*)(ws + OFF_WIH);
    unsigned short* whh_bf  = (unsigned short*)(ws + OFF_WHH);
    unsigned short* wph_bf  = (unsigned short*)(ws + OFF_WPH);
    unsigned short* frames  = (unsigned short*)(ws + OFF_FRM);
    unsigned short* xproj   = (unsigned short*)(ws + OFF_XPROJ);
    unsigned short* h_all   = (unsigned short*)(ws + OFF_HALL);
    unsigned int*   flags   = (unsigned int*)(ws + OFF_BAR);
    float*          ctxproj = (float*)(ws + OFF_CTX);
    float*          gctx    = (float*)(ws + OFF_GCTX);

    // per-call init (harness does not re-zero ws between replays)
    hipMemsetAsync(h_all, 0, (size_t)BB * RNN * 2, stream);   // h0 slot
    hipMemsetAsync(flags, 0, 4096, stream);                   // band flags

    k_f32_to_bf16<<<2048, 256, 0, stream>>>(W_ih, wih_bf, G4 * INDIM);
    k_f32_to_bf16<<<2048, 256, 0, stream>>>(W_hh, whh_bf, G4 * RNN);
    k_conv_wph<<<2048, 256, 0, stream>>>(W_proj, wph_bf);
    k_frames<<<2048, 256, 0, stream>>>(target, frames);
    k_ctxproj<<<(BB * INDIM + 255) / 256, 256, 0, stream>>>(context, W_proj,
                                                            b_proj, ctxproj);
    k_gatectx<<<1, 256, 0, stream>>>(context, W_gate, b_gate, gctx);

    k_gemm_xproj<<<dim3(G4 / 128, MROWS / 128), 256, 0, stream>>>(
        frames, wih_bf, b_ih, b_hh, xproj);

    k_recur<<<512, 512, 0, stream>>>(whh_bf, xproj, h_all, flags);

    k_gemm_mel<<<dim3(INDIM / 128, MROWS / 128), 256, 0, stream>>>(
        h_all + (size_t)BB * RNN, wph_bf, ctxproj, out);
    k_gate<<<MROWS / 4, 256, 0, stream>>>(h_all + (size_t)BB * RNN, W_gate,
                                          gctx, out + (size_t)BB * NMEL * TMEL);
}

// Round 10
// 939.032 us; speedup vs baseline: 1.6297x; 1.6297x over previous
//
#include <hip/hip_runtime.h>
#include <hip/hip_bf16.h>
#include <math.h>

// Problem constants
#define BB     256
#define NMEL   80
#define TMEL   800
#define NFR    16          // frames per step
#define TT     50          // decoder steps
#define RNN    1024
#define ENC    256
#define INDIM  1280        // RNN + ENC == MEL_DIM
#define G4     4096        // 4*RNN
#define MROWS  (TT*BB)     // 12800

typedef __attribute__((ext_vector_type(8))) short bf16x8;
typedef __attribute__((ext_vector_type(4))) float f32x4;

#define GAS __attribute__((address_space(1)))
#define LAS __attribute__((address_space(3)))

__device__ __forceinline__ unsigned short f2bf(float f) {
    unsigned int u = __float_as_uint(f);
    u += 0x7FFFu + ((u >> 16) & 1u);     // round-to-nearest-even
    return (unsigned short)(u >> 16);
}
__device__ __forceinline__ float bf2f(unsigned short s) {
    return __uint_as_float(((unsigned int)s) << 16);
}

// ---------------- prep kernels ----------------

__global__ void k_f32_to_bf16(const float* __restrict__ src,
                              unsigned short* __restrict__ dst, int n) {
    for (int i = blockIdx.x * blockDim.x + threadIdx.x; i < n;
         i += gridDim.x * blockDim.x)
        dst[i] = f2bf(src[i]);
}

// W_proj[:, 0:1024] -> bf16, N-permuted: dst row m' = mel*16+fr comes from
// W_proj row m = fr*80+mel. Makes mel-GEMM output contiguous along (t,fr).
__global__ void k_conv_wph(const float* __restrict__ wproj,
                           unsigned short* __restrict__ dst) {
    const int n = INDIM * RNN;
    for (int i = blockIdx.x * blockDim.x + threadIdx.x; i < n;
         i += gridDim.x * blockDim.x) {
        int mp = i >> 10, k = i & 1023;
        int mel = mp >> 4, fr = mp & 15;
        dst[i] = f2bf(wproj[(fr * NMEL + mel) * INDIM + k]);
    }
}

// teacher-forced inputs: frames[t][b][k] = (t==0)?0:target[b][k%80][t*16+k/80]
__global__ void k_frames(const float* __restrict__ target,
                         unsigned short* __restrict__ frames) {
    const int n = TT * BB * INDIM;
    for (int i = blockIdx.x * blockDim.x + threadIdx.x; i < n;
         i += gridDim.x * blockDim.x) {
        int k = i % INDIM;
        int rb = i / INDIM;
        int b = rb & (BB - 1);
        int t = rb >> 8;
        unsigned short v = 0;
        if (t > 0) {
            int mel = k % NMEL, fr = k / NMEL;
            v = f2bf(target[(b * NMEL + mel) * TMEL + t * NFR + fr]);
        }
        frames[i] = v;
    }
}

// ctxproj[b][m'] = b_proj[m] + context[b]·W_proj[m][1024:1280], m'=mel*16+fr,
// m = fr*80+mel (same permutation as k_conv_wph).
__global__ void k_ctxproj(const float* __restrict__ context,
                          const float* __restrict__ wproj,
                          const float* __restrict__ bproj,
                          float* __restrict__ ctx) {
    int i = blockIdx.x * blockDim.x + threadIdx.x;
    if (i >= BB * INDIM) return;
    int mp = i % INDIM, b = i / INDIM;
    int mel = mp >> 4, fr = mp & 15;
    int m = fr * NMEL + mel;
    const float* wr = wproj + (size_t)m * INDIM + RNN;
    const float* cb = context + b * ENC;
    float acc = bproj[m];
    for (int e = 0; e < ENC; ++e) acc += cb[e] * wr[e];
    ctx[(size_t)b * INDIM + mp] = acc;
}

// gatectx[b] = b_gate + context[b]·W_gate[0][1024:1280]
__global__ void k_gatectx(const float* __restrict__ context,
                          const float* __restrict__ wgate,
                          const float* __restrict__ bgate,
                          float* __restrict__ gctx) {
    int b = blockIdx.x * blockDim.x + threadIdx.x;
    if (b >= BB) return;
    float acc = bgate[0];
    const float* cb = context + b * ENC;
    for (int e = 0; e < ENC; ++e) acc += cb[e] * wgate[RNN + e];
    gctx[b] = acc;
}

// ---------------- m97-structure tile GEMM core ----------------
template<int STRIDE, int KDIM>
__device__ __forceinline__ void gemm_core(const unsigned short* __restrict__ A,
                                          const unsigned short* __restrict__ Bw,
                                          int mblk, int nblk,
                                          unsigned short* As, unsigned short* Bs,
                                          f32x4 acc[4][4]) {
    const int tid = threadIdx.x, lane = tid & 63, wid = tid >> 6;
    const int wm = (wid >> 1) * 64, wn = (wid & 1) * 64;
    const int lr = lane & 15, lko = (lane >> 4) * 8;
    const int c0 = wid * 128 + lane;          // call 0 chunk for this lane
    const int c1 = c0 + 64;                   // call 1
    const int r0 = c0 >> 2, o0 = (c0 & 3) * 8;
    const int r1 = c1 >> 2, o1 = (c1 & 3) * 8;
    const unsigned short* a0p = A + (size_t)(mblk + r0) * STRIDE + o0;
    const unsigned short* a1p = A + (size_t)(mblk + r1) * STRIDE + o1;
    const unsigned short* b0p = Bw + (size_t)(nblk + r0) * STRIDE + o0;
    const unsigned short* b1p = Bw + (size_t)(nblk + r1) * STRIDE + o1;
    unsigned short* da0 = As + wid * 1024;          // uniform per wave
    unsigned short* da1 = As + wid * 1024 + 512;
    unsigned short* db0 = Bs + wid * 1024;
    unsigned short* db1 = Bs + wid * 1024 + 512;
    for (int k0 = 0; k0 < KDIM; k0 += 32) {
        __syncthreads();   // previous compute done before LDS overwrite
        __builtin_amdgcn_global_load_lds((const GAS unsigned int*)(a0p + k0),
                                         (LAS unsigned int*)da0, 16, 0, 0);
        __builtin_amdgcn_global_load_lds((const GAS unsigned int*)(a1p + k0),
                                         (LAS unsigned int*)da1, 16, 0, 0);
        __builtin_amdgcn_global_load_lds((const GAS unsigned int*)(b0p + k0),
                                         (LAS unsigned int*)db0, 16, 0, 0);
        __builtin_amdgcn_global_load_lds((const GAS unsigned int*)(b1p + k0),
                                         (LAS unsigned int*)db1, 16, 0, 0);
        __syncthreads();   // compiler drains vmcnt before barrier
        bf16x8 af[4], bfv[4];
        #pragma unroll
        for (int mi = 0; mi < 4; ++mi)
            af[mi] = *(const bf16x8*)(As + (wm + mi * 16 + lr) * 32 + lko);
        #pragma unroll
        for (int ni = 0; ni < 4; ++ni)
            bfv[ni] = *(const bf16x8*)(Bs + (wn + ni * 16 + lr) * 32 + lko);
        #pragma unroll
        for (int mi = 0; mi < 4; ++mi)
            #pragma unroll
            for (int ni = 0; ni < 4; ++ni)
                acc[mi][ni] = __builtin_amdgcn_mfma_f32_16x16x32_bf16(
                    af[mi], bfv[ni], acc[mi][ni], 0, 0, 0);
    }
}

// GEMM 1: xproj = frames @ W_ih^T + b_ih + b_hh (bf16 out). M=12800 N=4096 K=1280
__global__ __launch_bounds__(256) void k_gemm_xproj(
    const unsigned short* __restrict__ A,   // [12800][1280]
    const unsigned short* __restrict__ Bw,  // [4096][1280]
    const float* __restrict__ b_ih, const float* __restrict__ b_hh,
    unsigned short* __restrict__ Cout)      // [12800][4096]
{
    __shared__ unsigned short As[4096], Bs[4096];
    f32x4 acc[4][4] = {};
    const int mblk = blockIdx.y * 128, nblk = blockIdx.x * 128;
    gemm_core<INDIM, INDIM>(A, Bw, mblk, nblk, As, Bs, acc);
    const int lane = threadIdx.x & 63, wid = threadIdx.x >> 6;
    const int wm = (wid >> 1) * 64, wn = (wid & 1) * 64, lr = lane & 15;
    #pragma unroll
    for (int ni = 0; ni < 4; ++ni) {
        const int col = nblk + wn + ni * 16 + lr;
        const float bias = b_ih[col] + b_hh[col];
        #pragma unroll
        for (int mi = 0; mi < 4; ++mi) {
            const int row0 = mblk + wm + mi * 16 + (lane >> 4) * 4;
            #pragma unroll
            for (int r = 0; r < 4; ++r)
                Cout[(size_t)(row0 + r) * G4 + col] = f2bf(acc[mi][ni][r] + bias);
        }
    }
}

// GEMM 2: mel = h_all[1:] @ Wp'^T + ctxproj', coalesced scatter via LDS
// transpose. M=12800, N=1280 (permuted col' = mel*16+fr), K=1024.
__global__ __launch_bounds__(256) void k_gemm_mel(
    const unsigned short* __restrict__ A,   // [12800][1024]
    const unsigned short* __restrict__ Bw,  // Wp' [1280][1024] (permuted)
    const float* __restrict__ ctxproj,      // [256][1280] (permuted)
    float* __restrict__ out0)               // [256][80][800]
{
    __shared__ unsigned short As[4096], Bs[4096];
    __shared__ float txp[4][16][20];        // per-wave transpose; 20: align+banks
    f32x4 acc[4][4] = {};
    const int mblk = blockIdx.y * 128, nblk = blockIdx.x * 128;
    gemm_core<RNN, RNN>(A, Bw, mblk, nblk, As, Bs, acc);
    const int lane = threadIdx.x & 63, wid = threadIdx.x >> 6;
    const int wm = (wid >> 1) * 64, wn = (wid & 1) * 64, lr = lane & 15;
    const int rbase = (lane >> 4) * 4;
    const int rowl = lane & 15, fq = lane >> 4;   // readback roles
    #pragma unroll
    for (int mi = 0; mi < 4; ++mi) {
        const int row0 = mblk + wm + mi * 16;     // 16 rows: same t, b0..b0+15
        const int t = row0 >> 8, b0 = row0 & 255;
        #pragma unroll
        for (int ni = 0; ni < 4; ++ni) {
            const int colbase = nblk + wn + ni * 16;  // one mel, fr 0..15
            const int mel = colbase >> 4;
            __syncthreads();                      // txp free for reuse
            #pragma unroll
            for (int r = 0; r < 4; ++r)
                txp[wid][rbase + r][lr] = acc[mi][ni][r];
            __syncthreads();                      // transpose visible
            const int bL = b0 + rowl;
            f32x4 v = *(const f32x4*)&txp[wid][rowl][fq * 4];
            f32x4 cx = *(const f32x4*)(ctxproj + (size_t)bL * INDIM +
                                       mel * 16 + fq * 4);
            *(f32x4*)(out0 + (size_t)(bL * NMEL + mel) * TMEL +
                      t * NFR + fq * 4) = v + cx;
        }
    }
}

// ---------------- per-step fused LSTM kernel (v6) ----------------
// 50-launch path (persistent/software barriers abandoned: 4 designs all
// ≥14us/step; launch boundary ~2.5us is cheaper).
// v4 tiling + v7/v8's proven counted-vmcnt 4-deep pipeline:
// Grid (64,4): n0 = bx*16 (16 cols x 4 gates), m0 = by*64 (batch rows).
// 512 thr = 8 waves: wave -> gate g = w&3, m-half mh = w>>2 (32 rows).
// BK=64, 4 buffers; every thread stages 1 A-chunk + 1 B-chunk per iter
// (wave-uniform vmcnt ladder 6,...,6,4,2,0; raw s_barrier; vmcnt(0) only
// at last iter). xproj staged via global_load_lds too (oldest op, lands
// by first wait) -> NO register global loads -> no compiler drains.
__global__ __launch_bounds__(512) void k_step(
    const unsigned short* __restrict__ Whh,     // [4096][1024] bf16
    const unsigned short* __restrict__ xproj_t, // [256][4096] bf16
    const unsigned short* __restrict__ h_prev,  // [256][1024] bf16
    unsigned short* __restrict__ h_next,        // [256][1024] bf16
    float* __restrict__ c)                      // [256][1024] f32
{
    __shared__ unsigned short Abuf[4][4096];    // h 64r x 64k per buf (8KB x4)
    __shared__ unsigned short Bbuf[4][4096];    // Whh 64vr x 64k per buf (8KB x4)
    __shared__ unsigned short xg[4096];         // xproj tile [4][64][16] (8KB)
    __shared__ float gates[4][64][17];          // 17.4KB, +1 pad
    const int tid = threadIdx.x, lane = tid & 63, w = tid >> 6;
    const int g = w & 3, mh = w >> 2;
    const int n0 = blockIdx.x * 16, m0 = blockIdx.y * 64;
    const int lr = lane & 15, q = lane >> 4;
    const int sx = lr & 7;

    // staging descriptors (1 chunk of 16B per thread per tile):
    // cc = tid; row/vrow = cc>>3, 16B-sub = cc&7; XOR-swizzled global source
    // (both-sides rule) matching the swizzled ds_read below.
    const int rowc = tid >> 3, s2 = tid & 7;
    const unsigned short* asrc = h_prev + (size_t)(m0 + rowc) * RNN +
                                 ((s2 ^ (rowc & 7)) * 8);
    const unsigned short* bsrc = Whh +
        (size_t)((rowc >> 4) * RNN + n0 + (rowc & 15)) * RNN +
        ((s2 ^ (rowc & 7)) * 8);
    // xg: chunk tid -> gate = tid>>7, row = (tid>>1)&63, half = tid&1
    const unsigned short* xsrc = xproj_t +
        (size_t)(m0 + ((tid >> 1) & 63)) * G4 + (tid >> 7) * RNN + n0 +
        (tid & 1) * 8;

#define STAGE(buf, k0) do {                                                    \
    __builtin_amdgcn_global_load_lds((const GAS unsigned int*)(asrc + (k0)),   \
        (LAS unsigned int*)&Abuf[buf][w * 512], 16, 0, 0);                     \
    __builtin_amdgcn_global_load_lds((const GAS unsigned int*)(bsrc + (k0)),   \
        (LAS unsigned int*)&Bbuf[buf][w * 512], 16, 0, 0); } while (0)

    // xg first (oldest op -> guaranteed landed by first vmcnt(6))
    __builtin_amdgcn_global_load_lds((const GAS unsigned int*)xsrc,
        (LAS unsigned int*)&xg[w * 512], 16, 0, 0);
    STAGE(0, 0); STAGE(1, 64); STAGE(2, 128);   // 3-ahead prologue

    const int swz_a0 = (mh * 32 + lr) * 64;
    const int swz_a1 = (mh * 32 + 16 + lr) * 64;
    const int swz_b  = (g * 16 + lr) * 64;

    f32x4 acc[2] = {};
    #pragma unroll
    for (int it = 0; it < 16; ++it) {
        if (it <= 12) STAGE((it + 3) & 3, (it + 3) * 64);
        // wait for stage(it); newer stages (only) stay in flight
        if (it <= 12)      asm volatile("s_waitcnt vmcnt(6)" ::: "memory");
        else if (it == 13) asm volatile("s_waitcnt vmcnt(4)" ::: "memory");
        else if (it == 14) asm volatile("s_waitcnt vmcnt(2)" ::: "memory");
        else               asm volatile("s_waitcnt vmcnt(0)" ::: "memory");
        asm volatile("s_barrier" ::: "memory");
        __builtin_amdgcn_sched_barrier(0);
        const unsigned short* Ab = Abuf[it & 3];
        const unsigned short* Bb = Bbuf[it & 3];
        #pragma unroll
        for (int ks = 0; ks < 2; ++ks) {
            const int sub = ks * 4 + q;
            bf16x8 a0 = *(const bf16x8*)(Ab + swz_a0 + ((sub ^ sx) * 8));
            bf16x8 a1 = *(const bf16x8*)(Ab + swz_a1 + ((sub ^ sx) * 8));
            bf16x8 bv = *(const bf16x8*)(Bb + swz_b + ((sub ^ sx) * 8));
            acc[0] = __builtin_amdgcn_mfma_f32_16x16x32_bf16(a0, bv, acc[0], 0, 0, 0);
            acc[1] = __builtin_amdgcn_mfma_f32_16x16x32_bf16(a1, bv, acc[1], 0, 0, 0);
        }
        asm volatile("s_waitcnt lgkmcnt(0)" ::: "memory");
        __builtin_amdgcn_sched_barrier(0);
        asm volatile("s_barrier" ::: "memory");
    }

    // epilogue: gates = acc + xg (wave-exclusive (g, mh) rows)
    #pragma unroll
    for (int mi = 0; mi < 2; ++mi)
        #pragma unroll
        for (int r = 0; r < 4; ++r) {
            const int row = mh * 32 + mi * 16 + q * 4 + r;
            gates[g][row][lr] = acc[mi][r] +
                bf2f(xg[(g * 64 + row) * 16 + lr]);
        }
    __syncthreads();

    // LSTM tail: 1024 elements (64x16), 2 per thread; c f32 global
    #pragma unroll
    for (int q2 = 0; q2 < 2; ++q2) {
        const int e = tid + q2 * 512;
        const int row = e >> 4, col = e & 15;
        const int b = m0 + row, j = n0 + col;
        const float xi = gates[0][row][col];
        const float xf = gates[1][row][col];
        const float xgt = gates[2][row][col];
        const float xo = gates[3][row][col];
        const float si = 1.f / (1.f + expf(-xi));
        const float sf = 1.f / (1.f + expf(-xf));
        const float so = 1.f / (1.f + expf(-xo));
        const float cp = c[(size_t)b * RNN + j];
        const float cn = sf * cp + si * tanhf(xgt);
        const float hn = so * tanhf(cn);
        c[(size_t)b * RNN + j] = cn;
        h_next[(size_t)b * RNN + j] = f2bf(hn);
    }
#undef STAGE
}

// gate[b*50+t] = gatectx[b] + h_all[t+1][b]·w_gate[0:1024] ; one wave per row
__global__ void k_gate(const unsigned short* __restrict__ h,  // [12800][1024]
                       const float* __restrict__ wgate,
                       const float* __restrict__ gctx,
                       float* __restrict__ out1) {
    const int gw = (blockIdx.x * blockDim.x + threadIdx.x) >> 6;
    const int lane = threadIdx.x & 63;
    if (gw >= MROWS) return;
    const unsigned short* hr = h + (size_t)gw * RNN + lane * 16;
    const float* wr = wgate + lane * 16;
    float acc = 0.f;
    #pragma unroll
    for (int j = 0; j < 16; ++j) acc += bf2f(hr[j]) * wr[j];
    for (int off = 32; off; off >>= 1) acc += __shfl_down(acc, off);
    if (lane == 0) {
        const int t = gw >> 8, b = gw & 255;
        out1[b * TT + t] = acc + gctx[b];
    }
}

// ---------------- workspace layout (all offsets 1KB-aligned) ----------------
static const size_t OFF_WIH   = 0;                                    // 10.5 MB
static const size_t OFF_WHH   = OFF_WIH   + (size_t)G4 * INDIM * 2;   // 8 MB
static const size_t OFF_WPH   = OFF_WHH   + (size_t)G4 * RNN * 2;     // 2.6 MB
static const size_t OFF_FRM   = OFF_WPH   + (size_t)INDIM * RNN * 2;  // 32.8 MB
static const size_t OFF_XPROJ = OFF_FRM   + (size_t)MROWS * INDIM * 2;// 104.9 MB
static const size_t OFF_HALL  = OFF_XPROJ + (size_t)MROWS * G4 * 2;   // 26.7 MB
static const size_t OFF_C     = OFF_HALL  + (size_t)(TT + 1) * BB * RNN * 2;
static const size_t OFF_CTX   = OFF_C     + (size_t)BB * RNN * 4;
static const size_t OFF_GCTX  = OFF_CTX   + (size_t)BB * INDIM * 4;

extern "C" void kernel_launch(void* const* d_in, const int* in_sizes, int n_in,
                              void* d_out, int out_size, void* d_ws, size_t ws_size,
                              hipStream_t stream) {
    const float* context = (const float*)d_in[0];
    const float* target  = (const float*)d_in[1];
    const float* W_ih    = (const float*)d_in[2];
    const float* b_ih    = (const float*)d_in[3];
    const float* W_hh    = (const float*)d_in[4];
    const float* b_hh    = (const float*)d_in[5];
    const float* W_proj  = (const float*)d_in[6];
    const float* b_proj  = (const float*)d_in[7];
    const float* W_gate  = (const float*)d_in[8];
    const float* b_gate  = (const float*)d_in[9];
    float* out = (float*)d_out;
    char* ws = (char*)d_ws;

    unsigned short* wih_bf  = (unsigned short*)(ws + OFF_WIH);
    unsigned short* whh_bf  = (unsigned short*)(ws + OFF_WHH);
    unsigned short* wph_bf  = (unsigned short*)(ws + OFF_WPH);
    unsigned short* frames  = (unsigned short*)(ws + OFF_FRM);
    unsigned short* xproj   = (unsigned short*)(ws + OFF_XPROJ);
    unsigned short* h_all   = (unsigned short*)(ws + OFF_HALL);
    float*          c_buf   = (float*)(ws + OFF_C);
    float*          ctxproj = (float*)(ws + OFF_CTX);
    float*          gctx    = (float*)(ws + OFF_GCTX);

    // per-call init (harness does not re-zero ws between replays)
    hipMemsetAsync(h_all, 0, (size_t)BB * RNN * 2, stream);   // h0 slot
    hipMemsetAsync(c_buf, 0, (size_t)BB * RNN * 4, stream);   // c0

    k_f32_to_bf16<<<2048, 256, 0, stream>>>(W_ih, wih_bf, G4 * INDIM);
    k_f32_to_bf16<<<2048, 256, 0, stream>>>(W_hh, whh_bf, G4 * RNN);
    k_conv_wph<<<2048, 256, 0, stream>>>(W_proj, wph_bf);
    k_frames<<<2048, 256, 0, stream>>>(target, frames);
    k_ctxproj<<<(BB * INDIM + 255) / 256, 256, 0, stream>>>(context, W_proj,
                                                            b_proj, ctxproj);
    k_gatectx<<<1, 256, 0, stream>>>(context, W_gate, b_gate, gctx);

    k_gemm_xproj<<<dim3(G4 / 128, MROWS / 128), 256, 0, stream>>>(
        frames, wih_bf, b_ih, b_hh, xproj);

    for (int t = 0; t < TT; ++t) {
        k_step<<<dim3(64, 4), 512, 0, stream>>>(
            whh_bf, xproj + (size_t)t * BB * G4,
            h_all + (size_t)t * BB * RNN,
            h_all + (size_t)(t + 1) * BB * RNN, c_buf);
    }

    k_gemm_mel<<<dim3(INDIM / 128, MROWS / 128), 256, 0, stream>>>(
        h_all + (size_t)BB * RNN, wph_bf, ctxproj, out);
    k_gate<<<MROWS / 4, 256, 0, stream>>>(h_all + (size_t)BB * RNN, W_gate,
                                          gctx, out + (size_t)BB * NMEL * TMEL);
}

// Round 11
// 856.936 us; speedup vs baseline: 1.7858x; 1.0958x over previous
//
#include <hip/hip_runtime.h>
#include <hip/hip_bf16.h>
#include <math.h>

// Problem constants
#define BB     256
#define NMEL   80
#define TMEL   800
#define NFR    16          // frames per step
#define TT     50          // decoder steps
#define RNN    1024
#define ENC    256
#define INDIM  1280        // RNN + ENC == MEL_DIM
#define G4     4096        // 4*RNN
#define MROWS  (TT*BB)     // 12800

typedef __attribute__((ext_vector_type(8))) short bf16x8;
typedef __attribute__((ext_vector_type(4))) float f32x4;

#define GAS __attribute__((address_space(1)))
#define LAS __attribute__((address_space(3)))

__device__ __forceinline__ unsigned short f2bf(float f) {
    unsigned int u = __float_as_uint(f);
    u += 0x7FFFu + ((u >> 16) & 1u);     // round-to-nearest-even
    return (unsigned short)(u >> 16);
}
__device__ __forceinline__ float bf2f(unsigned short s) {
    return __uint_as_float(((unsigned int)s) << 16);
}
__device__ __forceinline__ float fsig(float x) {      // inf-safe fast sigmoid
    return 1.f / (1.f + __expf(-x));
}
__device__ __forceinline__ float ftanh(float x) {     // tanh = 2*sig(2x)-1
    return 2.f / (1.f + __expf(-2.f * x)) - 1.f;
}

// ---------------- prep kernels ----------------

__global__ void k_f32_to_bf16(const float* __restrict__ src,
                              unsigned short* __restrict__ dst, int n) {
    for (int i = blockIdx.x * blockDim.x + threadIdx.x; i < n;
         i += gridDim.x * blockDim.x)
        dst[i] = f2bf(src[i]);
}

// W_proj[:, 0:1024] -> bf16, N-permuted: dst row m' = mel*16+fr comes from
// W_proj row m = fr*80+mel. Makes mel-GEMM output contiguous along (t,fr).
__global__ void k_conv_wph(const float* __restrict__ wproj,
                           unsigned short* __restrict__ dst) {
    const int n = INDIM * RNN;
    for (int i = blockIdx.x * blockDim.x + threadIdx.x; i < n;
         i += gridDim.x * blockDim.x) {
        int mp = i >> 10, k = i & 1023;
        int mel = mp >> 4, fr = mp & 15;
        dst[i] = f2bf(wproj[(fr * NMEL + mel) * INDIM + k]);
    }
}

// teacher-forced inputs: frames[t][b][k] = (t==0)?0:target[b][k%80][t*16+k/80]
__global__ void k_frames(const float* __restrict__ target,
                         unsigned short* __restrict__ frames) {
    const int n = TT * BB * INDIM;
    for (int i = blockIdx.x * blockDim.x + threadIdx.x; i < n;
         i += gridDim.x * blockDim.x) {
        int k = i % INDIM;
        int rb = i / INDIM;
        int b = rb & (BB - 1);
        int t = rb >> 8;
        unsigned short v = 0;
        if (t > 0) {
            int mel = k % NMEL, fr = k / NMEL;
            v = f2bf(target[(b * NMEL + mel) * TMEL + t * NFR + fr]);
        }
        frames[i] = v;
    }
}

// ctxproj[b][m'] = b_proj[m] + context[b]·W_proj[m][1024:1280], m'=mel*16+fr,
// m = fr*80+mel (same permutation as k_conv_wph).
__global__ void k_ctxproj(const float* __restrict__ context,
                          const float* __restrict__ wproj,
                          const float* __restrict__ bproj,
                          float* __restrict__ ctx) {
    int i = blockIdx.x * blockDim.x + threadIdx.x;
    if (i >= BB * INDIM) return;
    int mp = i % INDIM, b = i / INDIM;
    int mel = mp >> 4, fr = mp & 15;
    int m = fr * NMEL + mel;
    const float* wr = wproj + (size_t)m * INDIM + RNN;
    const float* cb = context + b * ENC;
    float acc = bproj[m];
    for (int e = 0; e < ENC; ++e) acc += cb[e] * wr[e];
    ctx[(size_t)b * INDIM + mp] = acc;
}

// gatectx[b] = b_gate + context[b]·W_gate[0][1024:1280]
__global__ void k_gatectx(const float* __restrict__ context,
                          const float* __restrict__ wgate,
                          const float* __restrict__ bgate,
                          float* __restrict__ gctx) {
    int b = blockIdx.x * blockDim.x + threadIdx.x;
    if (b >= BB) return;
    float acc = bgate[0];
    const float* cb = context + b * ENC;
    for (int e = 0; e < ENC; ++e) acc += cb[e] * wgate[RNN + e];
    gctx[b] = acc;
}

// ---------------- m97-structure tile GEMM core ----------------
template<int STRIDE, int KDIM>
__device__ __forceinline__ void gemm_core(const unsigned short* __restrict__ A,
                                          const unsigned short* __restrict__ Bw,
                                          int mblk, int nblk,
                                          unsigned short* As, unsigned short* Bs,
                                          f32x4 acc[4][4]) {
    const int tid = threadIdx.x, lane = tid & 63, wid = tid >> 6;
    const int wm = (wid >> 1) * 64, wn = (wid & 1) * 64;
    const int lr = lane & 15, lko = (lane >> 4) * 8;
    const int c0 = wid * 128 + lane;          // call 0 chunk for this lane
    const int c1 = c0 + 64;                   // call 1
    const int r0 = c0 >> 2, o0 = (c0 & 3) * 8;
    const int r1 = c1 >> 2, o1 = (c1 & 3) * 8;
    const unsigned short* a0p = A + (size_t)(mblk + r0) * STRIDE + o0;
    const unsigned short* a1p = A + (size_t)(mblk + r1) * STRIDE + o1;
    const unsigned short* b0p = Bw + (size_t)(nblk + r0) * STRIDE + o0;
    const unsigned short* b1p = Bw + (size_t)(nblk + r1) * STRIDE + o1;
    unsigned short* da0 = As + wid * 1024;          // uniform per wave
    unsigned short* da1 = As + wid * 1024 + 512;
    unsigned short* db0 = Bs + wid * 1024;
    unsigned short* db1 = Bs + wid * 1024 + 512;
    for (int k0 = 0; k0 < KDIM; k0 += 32) {
        __syncthreads();   // previous compute done before LDS overwrite
        __builtin_amdgcn_global_load_lds((const GAS unsigned int*)(a0p + k0),
                                         (LAS unsigned int*)da0, 16, 0, 0);
        __builtin_amdgcn_global_load_lds((const GAS unsigned int*)(a1p + k0),
                                         (LAS unsigned int*)da1, 16, 0, 0);
        __builtin_amdgcn_global_load_lds((const GAS unsigned int*)(b0p + k0),
                                         (LAS unsigned int*)db0, 16, 0, 0);
        __builtin_amdgcn_global_load_lds((const GAS unsigned int*)(b1p + k0),
                                         (LAS unsigned int*)db1, 16, 0, 0);
        __syncthreads();   // compiler drains vmcnt before barrier
        bf16x8 af[4], bfv[4];
        #pragma unroll
        for (int mi = 0; mi < 4; ++mi)
            af[mi] = *(const bf16x8*)(As + (wm + mi * 16 + lr) * 32 + lko);
        #pragma unroll
        for (int ni = 0; ni < 4; ++ni)
            bfv[ni] = *(const bf16x8*)(Bs + (wn + ni * 16 + lr) * 32 + lko);
        #pragma unroll
        for (int mi = 0; mi < 4; ++mi)
            #pragma unroll
            for (int ni = 0; ni < 4; ++ni)
                acc[mi][ni] = __builtin_amdgcn_mfma_f32_16x16x32_bf16(
                    af[mi], bfv[ni], acc[mi][ni], 0, 0, 0);
    }
}

// GEMM 1: xproj = frames @ W_ih^T + b_ih + b_hh (bf16 out). M=12800 N=4096 K=1280
__global__ __launch_bounds__(256) void k_gemm_xproj(
    const unsigned short* __restrict__ A,   // [12800][1280]
    const unsigned short* __restrict__ Bw,  // [4096][1280]
    const float* __restrict__ b_ih, const float* __restrict__ b_hh,
    unsigned short* __restrict__ Cout)      // [12800][4096]
{
    __shared__ unsigned short As[4096], Bs[4096];
    f32x4 acc[4][4] = {};
    const int mblk = blockIdx.y * 128, nblk = blockIdx.x * 128;
    gemm_core<INDIM, INDIM>(A, Bw, mblk, nblk, As, Bs, acc);
    const int lane = threadIdx.x & 63, wid = threadIdx.x >> 6;
    const int wm = (wid >> 1) * 64, wn = (wid & 1) * 64, lr = lane & 15;
    #pragma unroll
    for (int ni = 0; ni < 4; ++ni) {
        const int col = nblk + wn + ni * 16 + lr;
        const float bias = b_ih[col] + b_hh[col];
        #pragma unroll
        for (int mi = 0; mi < 4; ++mi) {
            const int row0 = mblk + wm + mi * 16 + (lane >> 4) * 4;
            #pragma unroll
            for (int r = 0; r < 4; ++r)
                Cout[(size_t)(row0 + r) * G4 + col] = f2bf(acc[mi][ni][r] + bias);
        }
    }
}

// GEMM 2: mel = h_all[1:] @ Wp'^T + ctxproj', coalesced scatter via LDS
// transpose. M=12800, N=1280 (permuted col' = mel*16+fr), K=1024.
__global__ __launch_bounds__(256) void k_gemm_mel(
    const unsigned short* __restrict__ A,   // [12800][1024]
    const unsigned short* __restrict__ Bw,  // Wp' [1280][1024] (permuted)
    const float* __restrict__ ctxproj,      // [256][1280] (permuted)
    float* __restrict__ out0)               // [256][80][800]
{
    __shared__ unsigned short As[4096], Bs[4096];
    __shared__ float txp[4][16][20];        // per-wave transpose; 20: align+banks
    f32x4 acc[4][4] = {};
    const int mblk = blockIdx.y * 128, nblk = blockIdx.x * 128;
    gemm_core<RNN, RNN>(A, Bw, mblk, nblk, As, Bs, acc);
    const int lane = threadIdx.x & 63, wid = threadIdx.x >> 6;
    const int wm = (wid >> 1) * 64, wn = (wid & 1) * 64, lr = lane & 15;
    const int rbase = (lane >> 4) * 4;
    const int rowl = lane & 15, fq = lane >> 4;   // readback roles
    #pragma unroll
    for (int mi = 0; mi < 4; ++mi) {
        const int row0 = mblk + wm + mi * 16;     // 16 rows: same t, b0..b0+15
        const int t = row0 >> 8, b0 = row0 & 255;
        #pragma unroll
        for (int ni = 0; ni < 4; ++ni) {
            const int colbase = nblk + wn + ni * 16;  // one mel, fr 0..15
            const int mel = colbase >> 4;
            __syncthreads();                      // txp free for reuse
            #pragma unroll
            for (int r = 0; r < 4; ++r)
                txp[wid][rbase + r][lr] = acc[mi][ni][r];
            __syncthreads();                      // transpose visible
            const int bL = b0 + rowl;
            f32x4 v = *(const f32x4*)&txp[wid][rowl][fq * 4];
            f32x4 cx = *(const f32x4*)(ctxproj + (size_t)bL * INDIM +
                                       mel * 16 + fq * 4);
            *(f32x4*)(out0 + (size_t)(bL * NMEL + mel) * TMEL +
                      t * NFR + fq * 4) = v + cx;
        }
    }
}

// ---------------- per-step fused LSTM kernel (v7) ----------------
// v6 skeleton with: BK=128 / 8 iters / 3 buffers (halves barrier count:
// 32 -> 16 raw s_barriers), 16-sub XOR swizzle, c prefetched to LDS via
// global_load_lds (issued first -> lands by the first counted wait; removes
// the dependent global c load from the tail), __expf-based activations.
// Grid (64,4): n0 = bx*16 (16 cols x 4 gates), m0 = by*64 (batch rows).
// 512 thr = 8 waves: wave -> gate g = w&3, m-half mh = w>>2 (32 rows).
// vmcnt ladder (2-deep, 4 stage-ops/iter): iters 0-5 vmcnt(8), 6: (4), 7: (0).
__global__ __launch_bounds__(512) void k_step(
    const unsigned short* __restrict__ Whh,     // [4096][1024] bf16
    const unsigned short* __restrict__ xproj_t, // [256][4096] bf16
    const unsigned short* __restrict__ h_prev,  // [256][1024] bf16
    unsigned short* __restrict__ h_next,        // [256][1024] bf16
    float* __restrict__ c)                      // [256][1024] f32
{
    __shared__ unsigned short Abuf[3][8192];    // h 64r x 128k per buf (16KB x3)
    __shared__ unsigned short Bbuf[3][8192];    // Whh 64vr x 128k per buf (16KB x3)
    __shared__ unsigned short xg[4096];         // xproj tile [4][64][16] (8KB)
    __shared__ float cld[64][16];               // cell state tile (4KB)
    __shared__ float gates[4][64][17];          // 17.4KB, +1 pad
    const int tid = threadIdx.x, lane = tid & 63, w = tid >> 6;
    const int g = w & 3, mh = w >> 2;
    const int n0 = blockIdx.x * 16, m0 = blockIdx.y * 64;
    const int lr = lane & 15, q = lane >> 4;

    // staging: chunk cc in [0,1024): row = cc>>4, LDS-sub = cc&15,
    // global sub = (cc&15) ^ (row&15)  [both-sides XOR swizzle].
    // Each thread stages chunks tid and tid+512 for A and for B (4 ops/iter).
    const int cc1 = tid, cc2 = tid + 512;
    const int r1 = cc1 >> 4, s1g = (cc1 & 15) ^ (r1 & 15);
    const int r2 = cc2 >> 4, s2g = (cc2 & 15) ^ (r2 & 15);
    const unsigned short* a1src = h_prev + (size_t)(m0 + r1) * RNN + s1g * 8;
    const unsigned short* a2src = h_prev + (size_t)(m0 + r2) * RNN + s2g * 8;
    const unsigned short* b1src = Whh +
        (size_t)((r1 >> 4) * RNN + n0 + (r1 & 15)) * RNN + s1g * 8;
    const unsigned short* b2src = Whh +
        (size_t)((r2 >> 4) * RNN + n0 + (r2 & 15)) * RNN + s2g * 8;
    // xg: chunk tid -> gate = tid>>7, row = (tid>>1)&63, half = tid&1
    const unsigned short* xsrc = xproj_t +
        (size_t)(m0 + ((tid >> 1) & 63)) * G4 + (tid >> 7) * RNN + n0 +
        (tid & 1) * 8;
    // c prefetch (threads 0..255): chunk -> row = tid>>2, 4-float col = tid&3
    const float* csrc = c + (size_t)(m0 + (tid >> 2)) * RNN + n0 + (tid & 3) * 4;

#define STAGE(buf, k0) do {                                                    \
    __builtin_amdgcn_global_load_lds((const GAS unsigned int*)(a1src + (k0)),  \
        (LAS unsigned int*)&Abuf[buf][w * 512], 16, 0, 0);                     \
    __builtin_amdgcn_global_load_lds((const GAS unsigned int*)(a2src + (k0)),  \
        (LAS unsigned int*)&Abuf[buf][4096 + w * 512], 16, 0, 0);              \
    __builtin_amdgcn_global_load_lds((const GAS unsigned int*)(b1src + (k0)),  \
        (LAS unsigned int*)&Bbuf[buf][w * 512], 16, 0, 0);                     \
    __builtin_amdgcn_global_load_lds((const GAS unsigned int*)(b2src + (k0)),  \
        (LAS unsigned int*)&Bbuf[buf][4096 + w * 512], 16, 0, 0); } while (0)

    // oldest ops first: c (tail input), xg (epilogue input) — both landed by
    // the first vmcnt(8); then the 2-tile prologue.
    if (w < 4)
        __builtin_amdgcn_global_load_lds((const GAS unsigned int*)csrc,
            (LAS unsigned int*)&cld[w * 16][0], 16, 0, 0);
    __builtin_amdgcn_global_load_lds((const GAS unsigned int*)xsrc,
        (LAS unsigned int*)&xg[w * 512], 16, 0, 0);
    STAGE(0, 0); STAGE(1, 128);

    f32x4 acc[2] = {};
    #pragma unroll
    for (int it = 0; it < 8; ++it) {
        if (it <= 5) STAGE((it + 2) % 3, (it + 2) * 128);
        // wait for stage(it); newer stages (only) stay in flight
        if (it <= 5)      asm volatile("s_waitcnt vmcnt(8)" ::: "memory");
        else if (it == 6) asm volatile("s_waitcnt vmcnt(4)" ::: "memory");
        else              asm volatile("s_waitcnt vmcnt(0)" ::: "memory");
        asm volatile("s_barrier" ::: "memory");
        __builtin_amdgcn_sched_barrier(0);
        const unsigned short* Ab = Abuf[it % 3];
        const unsigned short* Bb = Bbuf[it % 3];
        #pragma unroll
        for (int ks = 0; ks < 4; ++ks) {
            const int j = ((ks * 4 + q) ^ lr) * 8;   // swizzled 16B sub-chunk
            bf16x8 a0 = *(const bf16x8*)(Ab + (mh * 32 + lr) * 128 + j);
            bf16x8 a1 = *(const bf16x8*)(Ab + (mh * 32 + 16 + lr) * 128 + j);
            bf16x8 bv = *(const bf16x8*)(Bb + (g * 16 + lr) * 128 + j);
            acc[0] = __builtin_amdgcn_mfma_f32_16x16x32_bf16(a0, bv, acc[0], 0, 0, 0);
            acc[1] = __builtin_amdgcn_mfma_f32_16x16x32_bf16(a1, bv, acc[1], 0, 0, 0);
        }
        asm volatile("s_waitcnt lgkmcnt(0)" ::: "memory");
        __builtin_amdgcn_sched_barrier(0);
        asm volatile("s_barrier" ::: "memory");
    }

    // epilogue: gates = acc + xg (wave-exclusive (g, mh) rows)
    #pragma unroll
    for (int mi = 0; mi < 2; ++mi)
        #pragma unroll
        for (int r = 0; r < 4; ++r) {
            const int row = mh * 32 + mi * 16 + q * 4 + r;
            gates[g][row][lr] = acc[mi][r] +
                bf2f(xg[(g * 64 + row) * 16 + lr]);
        }
    __syncthreads();

    // LSTM tail: 1024 elements (64x16), 2 per thread; c from LDS prefetch
    #pragma unroll
    for (int q2 = 0; q2 < 2; ++q2) {
        const int e = tid + q2 * 512;
        const int row = e >> 4, col = e & 15;
        const int b = m0 + row, j = n0 + col;
        const float xi = gates[0][row][col];
        const float xf = gates[1][row][col];
        const float xgt = gates[2][row][col];
        const float xo = gates[3][row][col];
        const float si = fsig(xi);
        const float sf = fsig(xf);
        const float so = fsig(xo);
        const float cp = cld[row][col];
        const float cn = sf * cp + si * ftanh(xgt);
        const float hn = so * ftanh(cn);
        c[(size_t)b * RNN + j] = cn;
        h_next[(size_t)b * RNN + j] = f2bf(hn);
    }
#undef STAGE
}

// gate[b*50+t] = gatectx[b] + h_all[t+1][b]·w_gate[0:1024] ; one wave per row
__global__ void k_gate(const unsigned short* __restrict__ h,  // [12800][1024]
                       const float* __restrict__ wgate,
                       const float* __restrict__ gctx,
                       float* __restrict__ out1) {
    const int gw = (blockIdx.x * blockDim.x + threadIdx.x) >> 6;
    const int lane = threadIdx.x & 63;
    if (gw >= MROWS) return;
    const unsigned short* hr = h + (size_t)gw * RNN + lane * 16;
    const float* wr = wgate + lane * 16;
    float acc = 0.f;
    #pragma unroll
    for (int j = 0; j < 16; ++j) acc += bf2f(hr[j]) * wr[j];
    for (int off = 32; off; off >>= 1) acc += __shfl_down(acc, off);
    if (lane == 0) {
        const int t = gw >> 8, b = gw & 255;
        out1[b * TT + t] = acc + gctx[b];
    }
}

// ---------------- workspace layout (all offsets 1KB-aligned) ----------------
static const size_t OFF_WIH   = 0;                                    // 10.5 MB
static const size_t OFF_WHH   = OFF_WIH   + (size_t)G4 * INDIM * 2;   // 8 MB
static const size_t OFF_WPH   = OFF_WHH   + (size_t)G4 * RNN * 2;     // 2.6 MB
static const size_t OFF_FRM   = OFF_WPH   + (size_t)INDIM * RNN * 2;  // 32.8 MB
static const size_t OFF_XPROJ = OFF_FRM   + (size_t)MROWS * INDIM * 2;// 104.9 MB
static const size_t OFF_HALL  = OFF_XPROJ + (size_t)MROWS * G4 * 2;   // 26.7 MB
static const size_t OFF_C     = OFF_HALL  + (size_t)(TT + 1) * BB * RNN * 2;
static const size_t OFF_CTX   = OFF_C     + (size_t)BB * RNN * 4;
static const size_t OFF_GCTX  = OFF_CTX   + (size_t)BB * INDIM * 4;

extern "C" void kernel_launch(void* const* d_in, const int* in_sizes, int n_in,
                              void* d_out, int out_size, void* d_ws, size_t ws_size,
                              hipStream_t stream) {
    const float* context = (const float*)d_in[0];
    const float* target  = (const float*)d_in[1];
    const float* W_ih    = (const float*)d_in[2];
    const float* b_ih    = (const float*)d_in[3];
    const float* W_hh    = (const float*)d_in[4];
    const float* b_hh    = (const float*)d_in[5];
    const float* W_proj  = (const float*)d_in[6];
    const float* b_proj  = (const float*)d_in[7];
    const float* W_gate  = (const float*)d_in[8];
    const float* b_gate  = (const float*)d_in[9];
    float* out = (float*)d_out;
    char* ws = (char*)d_ws;

    unsigned short* wih_bf  = (unsigned short*)(ws + OFF_WIH);
    unsigned short* whh_bf  = (unsigned short*)(ws + OFF_WHH);
    unsigned short* wph_bf  = (unsigned short*)(ws + OFF_WPH);
    unsigned short* frames  = (unsigned short*)(ws + OFF_FRM);
    unsigned short* xproj   = (unsigned short*)(ws + OFF_XPROJ);
    unsigned short* h_all   = (unsigned short*)(ws + OFF_HALL);
    float*          c_buf   = (float*)(ws + OFF_C);
    float*          ctxproj = (float*)(ws + OFF_CTX);
    float*          gctx    = (float*)(ws + OFF_GCTX);

    // per-call init (harness does not re-zero ws between replays)
    hipMemsetAsync(h_all, 0, (size_t)BB * RNN * 2, stream);   // h0 slot
    hipMemsetAsync(c_buf, 0, (size_t)BB * RNN * 4, stream);   // c0

    k_f32_to_bf16<<<2048, 256, 0, stream>>>(W_ih, wih_bf, G4 * INDIM);
    k_f32_to_bf16<<<2048, 256, 0, stream>>>(W_hh, whh_bf, G4 * RNN);
    k_conv_wph<<<2048, 256, 0, stream>>>(W_proj, wph_bf);
    k_frames<<<2048, 256, 0, stream>>>(target, frames);
    k_ctxproj<<<(BB * INDIM + 255) / 256, 256, 0, stream>>>(context, W_proj,
                                                            b_proj, ctxproj);
    k_gatectx<<<1, 256, 0, stream>>>(context, W_gate, b_gate, gctx);

    k_gemm_xproj<<<dim3(G4 / 128, MROWS / 128), 256, 0, stream>>>(
        frames, wih_bf, b_ih, b_hh, xproj);

    for (int t = 0; t < TT; ++t) {
        k_step<<<dim3(64, 4), 512, 0, stream>>>(
            whh_bf, xproj + (size_t)t * BB * G4,
            h_all + (size_t)t * BB * RNN,
            h_all + (size_t)(t + 1) * BB * RNN, c_buf);
    }

    k_gemm_mel<<<dim3(INDIM / 128, MROWS / 128), 256, 0, stream>>>(
        h_all + (size_t)BB * RNN, wph_bf, ctxproj, out);
    k_gate<<<MROWS / 4, 256, 0, stream>>>(h_all + (size_t)BB * RNN, W_gate,
                                          gctx, out + (size_t)BB * NMEL * TMEL);
}

// Round 12
// 825.064 us; speedup vs baseline: 1.8548x; 1.0386x over previous
//
#include <hip/hip_runtime.h>
#include <hip/hip_bf16.h>
#include <math.h>

// Problem constants
#define BB     256
#define NMEL   80
#define TMEL   800
#define NFR    16          // frames per step
#define TT     50          // decoder steps
#define RNN    1024
#define ENC    256
#define INDIM  1280        // RNN + ENC == MEL_DIM
#define G4     4096        // 4*RNN
#define MROWS  (TT*BB)     // 12800

typedef __attribute__((ext_vector_type(8))) short bf16x8;
typedef __attribute__((ext_vector_type(4))) float f32x4;

#define GAS __attribute__((address_space(1)))
#define LAS __attribute__((address_space(3)))

__device__ __forceinline__ unsigned short f2bf(float f) {
    unsigned int u = __float_as_uint(f);
    u += 0x7FFFu + ((u >> 16) & 1u);     // round-to-nearest-even
    return (unsigned short)(u >> 16);
}
__device__ __forceinline__ float bf2f(unsigned short s) {
    return __uint_as_float(((unsigned int)s) << 16);
}
__device__ __forceinline__ float fsig(float x) {      // inf-safe fast sigmoid
    return 1.f / (1.f + __expf(-x));
}
__device__ __forceinline__ float ftanh(float x) {     // tanh = 2*sig(2x)-1
    return 2.f / (1.f + __expf(-2.f * x)) - 1.f;
}

// ---------------- prep kernels ----------------

__global__ void k_f32_to_bf16(const float* __restrict__ src,
                              unsigned short* __restrict__ dst, int n) {
    for (int i = blockIdx.x * blockDim.x + threadIdx.x; i < n;
         i += gridDim.x * blockDim.x)
        dst[i] = f2bf(src[i]);
}

// W_proj[:, 0:1024] -> bf16, N-permuted: dst row m' = mel*16+fr comes from
// W_proj row m = fr*80+mel. Makes mel-GEMM output contiguous along (t,fr).
__global__ void k_conv_wph(const float* __restrict__ wproj,
                           unsigned short* __restrict__ dst) {
    const int n = INDIM * RNN;
    for (int i = blockIdx.x * blockDim.x + threadIdx.x; i < n;
         i += gridDim.x * blockDim.x) {
        int mp = i >> 10, k = i & 1023;
        int mel = mp >> 4, fr = mp & 15;
        dst[i] = f2bf(wproj[(fr * NMEL + mel) * INDIM + k]);
    }
}

// teacher-forced inputs: frames[t][b][k] = (t==0)?0:target[b][k%80][t*16+k/80]
__global__ void k_frames(const float* __restrict__ target,
                         unsigned short* __restrict__ frames) {
    const int n = TT * BB * INDIM;
    for (int i = blockIdx.x * blockDim.x + threadIdx.x; i < n;
         i += gridDim.x * blockDim.x) {
        int k = i % INDIM;
        int rb = i / INDIM;
        int b = rb & (BB - 1);
        int t = rb >> 8;
        unsigned short v = 0;
        if (t > 0) {
            int mel = k % NMEL, fr = k / NMEL;
            v = f2bf(target[(b * NMEL + mel) * TMEL + t * NFR + fr]);
        }
        frames[i] = v;
    }
}

// ctxproj[b][m'] = b_proj[m] + context[b]·W_proj[m][1024:1280], m'=mel*16+fr,
// m = fr*80+mel (same permutation as k_conv_wph).
__global__ void k_ctxproj(const float* __restrict__ context,
                          const float* __restrict__ wproj,
                          const float* __restrict__ bproj,
                          float* __restrict__ ctx) {
    int i = blockIdx.x * blockDim.x + threadIdx.x;
    if (i >= BB * INDIM) return;
    int mp = i % INDIM, b = i / INDIM;
    int mel = mp >> 4, fr = mp & 15;
    int m = fr * NMEL + mel;
    const float* wr = wproj + (size_t)m * INDIM + RNN;
    const float* cb = context + b * ENC;
    float acc = bproj[m];
    for (int e = 0; e < ENC; ++e) acc += cb[e] * wr[e];
    ctx[(size_t)b * INDIM + mp] = acc;
}

// gatectx[b] = b_gate + context[b]·W_gate[0][1024:1280]
__global__ void k_gatectx(const float* __restrict__ context,
                          const float* __restrict__ wgate,
                          const float* __restrict__ bgate,
                          float* __restrict__ gctx) {
    int b = blockIdx.x * blockDim.x + threadIdx.x;
    if (b >= BB) return;
    float acc = bgate[0];
    const float* cb = context + b * ENC;
    for (int e = 0; e < ENC; ++e) acc += cb[e] * wgate[RNN + e];
    gctx[b] = acc;
}

// ---------------- GEMM core v2 (k_step-v6/v7 recipe transferred) ----------
// 128x128 WG tile, BK=64, 512 thr / 8 waves (wave -> 64x32 output).
// Both-sides 8-sub XOR swizzle -> conflict-free ds_read_b128.
// 2-buffer counted-vmcnt pipeline: raw s_barrier, vmcnt(4) steady state
// (next tile's 4 staging ops stay in flight), vmcnt(0) only at last iter.
// LDS 64KB -> 2 WG/CU; partner WG covers the 1-deep prefetch stall.
template<int STRIDE, int KDIM>
__device__ __forceinline__ void gemm_core2(const unsigned short* __restrict__ A,
                                           const unsigned short* __restrict__ Bw,
                                           int mblk, int nblk,
                                           unsigned short* As,   // [2][8192]
                                           unsigned short* Bs,   // [2][8192]
                                           f32x4 acc[4][2]) {
    const int tid = threadIdx.x, lane = tid & 63, w = tid >> 6;
    const int lr = lane & 15, q = lane >> 4;
    const int wm = (w >> 2) * 64, wn = (w & 3) * 32;
    // staging: tile = 1024 chunks of 16B (row = cc>>3 in [0,128), sub = cc&7);
    // global sub XOR row&7 (both-sides swizzle). Each thread: chunks tid, tid+512.
    const int cc1 = tid, cc2 = tid + 512;
    const int r1 = cc1 >> 3, s1 = ((cc1 & 7) ^ (r1 & 7)) * 8;
    const int r2 = cc2 >> 3, s2 = ((cc2 & 7) ^ (r2 & 7)) * 8;
    const unsigned short* a1p = A + (size_t)(mblk + r1) * STRIDE + s1;
    const unsigned short* a2p = A + (size_t)(mblk + r2) * STRIDE + s2;
    const unsigned short* b1p = Bw + (size_t)(nblk + r1) * STRIDE + s1;
    const unsigned short* b2p = Bw + (size_t)(nblk + r2) * STRIDE + s2;

#define GSTAGE(buf, k0) do {                                                   \
    __builtin_amdgcn_global_load_lds((const GAS unsigned int*)(a1p + (k0)),    \
        (LAS unsigned int*)(As + (buf) * 8192 + w * 512), 16, 0, 0);           \
    __builtin_amdgcn_global_load_lds((const GAS unsigned int*)(a2p + (k0)),    \
        (LAS unsigned int*)(As + (buf) * 8192 + 4096 + w * 512), 16, 0, 0);    \
    __builtin_amdgcn_global_load_lds((const GAS unsigned int*)(b1p + (k0)),    \
        (LAS unsigned int*)(Bs + (buf) * 8192 + w * 512), 16, 0, 0);           \
    __builtin_amdgcn_global_load_lds((const GAS unsigned int*)(b2p + (k0)),    \
        (LAS unsigned int*)(Bs + (buf) * 8192 + 4096 + w * 512), 16, 0, 0); } while (0)

    constexpr int NIT = KDIM / 64;
    GSTAGE(0, 0);
    #pragma unroll 4
    for (int it = 0; it < NIT; ++it) {
        if (it < NIT - 1) {
            GSTAGE((it + 1) & 1, (it + 1) * 64);
            asm volatile("s_waitcnt vmcnt(4)" ::: "memory");
        } else {
            asm volatile("s_waitcnt vmcnt(0)" ::: "memory");
        }
        asm volatile("s_barrier" ::: "memory");
        __builtin_amdgcn_sched_barrier(0);
        const unsigned short* Ab = As + (it & 1) * 8192;
        const unsigned short* Bb = Bs + (it & 1) * 8192;
        #pragma unroll
        for (int ks = 0; ks < 2; ++ks) {
            const int j = (((ks * 4 + q) ^ (lr & 7)) * 8);  // swizzled 16B sub
            bf16x8 af[4], bv[2];
            #pragma unroll
            for (int mi = 0; mi < 4; ++mi)
                af[mi] = *(const bf16x8*)(Ab + (wm + mi * 16 + lr) * 64 + j);
            #pragma unroll
            for (int ni = 0; ni < 2; ++ni)
                bv[ni] = *(const bf16x8*)(Bb + (wn + ni * 16 + lr) * 64 + j);
            #pragma unroll
            for (int mi = 0; mi < 4; ++mi)
                #pragma unroll
                for (int ni = 0; ni < 2; ++ni)
                    acc[mi][ni] = __builtin_amdgcn_mfma_f32_16x16x32_bf16(
                        af[mi], bv[ni], acc[mi][ni], 0, 0, 0);
        }
        asm volatile("s_waitcnt lgkmcnt(0)" ::: "memory");
        __builtin_amdgcn_sched_barrier(0);
        asm volatile("s_barrier" ::: "memory");
    }
#undef GSTAGE
}

// GEMM 1: xproj = frames @ W_ih^T + b_ih + b_hh (bf16 out). M=12800 N=4096 K=1280
__global__ __launch_bounds__(512) void k_gemm_xproj(
    const unsigned short* __restrict__ A,   // [12800][1280]
    const unsigned short* __restrict__ Bw,  // [4096][1280]
    const float* __restrict__ b_ih, const float* __restrict__ b_hh,
    unsigned short* __restrict__ Cout)      // [12800][4096]
{
    __shared__ unsigned short As[2][8192], Bs[2][8192];   // 64KB
    f32x4 acc[4][2] = {};
    const int mblk = blockIdx.y * 128, nblk = blockIdx.x * 128;
    gemm_core2<INDIM, INDIM>(A, Bw, mblk, nblk, &As[0][0], &Bs[0][0], acc);
    const int lane = threadIdx.x & 63, w = threadIdx.x >> 6;
    const int wm = (w >> 2) * 64, wn = (w & 3) * 32;
    const int lr = lane & 15, q = lane >> 4;
    #pragma unroll
    for (int ni = 0; ni < 2; ++ni) {
        const int col = nblk + wn + ni * 16 + lr;
        const float bias = b_ih[col] + b_hh[col];
        #pragma unroll
        for (int mi = 0; mi < 4; ++mi) {
            const int row0 = mblk + wm + mi * 16 + q * 4;
            #pragma unroll
            for (int r = 0; r < 4; ++r)
                Cout[(size_t)(row0 + r) * G4 + col] = f2bf(acc[mi][ni][r] + bias);
        }
    }
}

// GEMM 2: mel = h_all[1:] @ Wp'^T + ctxproj', coalesced scatter via LDS
// transpose. M=12800, N=1280 (permuted col' = mel*16+fr), K=1024.
__global__ __launch_bounds__(512) void k_gemm_mel(
    const unsigned short* __restrict__ A,   // [12800][1024]
    const unsigned short* __restrict__ Bw,  // Wp' [1280][1024] (permuted)
    const float* __restrict__ ctxproj,      // [256][1280] (permuted)
    float* __restrict__ out0)               // [256][80][800]
{
    __shared__ unsigned short As[2][8192], Bs[2][8192];   // 64KB
    __shared__ float txp[8][16][20];        // per-wave transpose (10.25KB)
    f32x4 acc[4][2] = {};
    const int mblk = blockIdx.y * 128, nblk = blockIdx.x * 128;
    gemm_core2<RNN, RNN>(A, Bw, mblk, nblk, &As[0][0], &Bs[0][0], acc);
    const int lane = threadIdx.x & 63, w = threadIdx.x >> 6;
    const int wm = (w >> 2) * 64, wn = (w & 3) * 32;
    const int lr = lane & 15, q = lane >> 4;
    const int rbase = q * 4;
    const int rowl = lane & 15, fq = lane >> 4;   // readback roles
    #pragma unroll
    for (int mi = 0; mi < 4; ++mi) {
        const int row0 = mblk + wm + mi * 16;     // 16 rows: same t, b0..b0+15
        const int t = row0 >> 8, b0 = row0 & 255;
        #pragma unroll
        for (int ni = 0; ni < 2; ++ni) {
            const int colbase = nblk + wn + ni * 16;  // one mel, fr 0..15
            const int mel = colbase >> 4;
            __syncthreads();                      // txp free for reuse
            #pragma unroll
            for (int r = 0; r < 4; ++r)
                txp[w][rbase + r][lr] = acc[mi][ni][r];
            __syncthreads();                      // transpose visible
            const int bL = b0 + rowl;
            f32x4 v = *(const f32x4*)&txp[w][rowl][fq * 4];
            f32x4 cx = *(const f32x4*)(ctxproj + (size_t)bL * INDIM +
                                       mel * 16 + fq * 4);
            *(f32x4*)(out0 + (size_t)(bL * NMEL + mel) * TMEL +
                      t * NFR + fq * 4) = v + cx;
        }
    }
}

// ---------------- per-step fused LSTM kernel (v7) ----------------
// BK=128 / 8 iters / 3 buffers, 16-sub XOR swizzle, c prefetched to LDS,
// __expf activations. Grid (64,4), 512 thr = 8 waves: g = w&3, mh = w>>2.
// vmcnt ladder (2-deep, 4 stage-ops/iter): iters 0-5 vmcnt(8), 6: (4), 7: (0).
__global__ __launch_bounds__(512) void k_step(
    const unsigned short* __restrict__ Whh,     // [4096][1024] bf16
    const unsigned short* __restrict__ xproj_t, // [256][4096] bf16
    const unsigned short* __restrict__ h_prev,  // [256][1024] bf16
    unsigned short* __restrict__ h_next,        // [256][1024] bf16
    float* __restrict__ c)                      // [256][1024] f32
{
    __shared__ unsigned short Abuf[3][8192];    // h 64r x 128k per buf (16KB x3)
    __shared__ unsigned short Bbuf[3][8192];    // Whh 64vr x 128k per buf (16KB x3)
    __shared__ unsigned short xg[4096];         // xproj tile [4][64][16] (8KB)
    __shared__ float cld[64][16];               // cell state tile (4KB)
    __shared__ float gates[4][64][17];          // 17.4KB, +1 pad
    const int tid = threadIdx.x, lane = tid & 63, w = tid >> 6;
    const int g = w & 3, mh = w >> 2;
    const int n0 = blockIdx.x * 16, m0 = blockIdx.y * 64;
    const int lr = lane & 15, q = lane >> 4;

    const int cc1 = tid, cc2 = tid + 512;
    const int r1 = cc1 >> 4, s1g = (cc1 & 15) ^ (r1 & 15);
    const int r2 = cc2 >> 4, s2g = (cc2 & 15) ^ (r2 & 15);
    const unsigned short* a1src = h_prev + (size_t)(m0 + r1) * RNN + s1g * 8;
    const unsigned short* a2src = h_prev + (size_t)(m0 + r2) * RNN + s2g * 8;
    const unsigned short* b1src = Whh +
        (size_t)((r1 >> 4) * RNN + n0 + (r1 & 15)) * RNN + s1g * 8;
    const unsigned short* b2src = Whh +
        (size_t)((r2 >> 4) * RNN + n0 + (r2 & 15)) * RNN + s2g * 8;
    const unsigned short* xsrc = xproj_t +
        (size_t)(m0 + ((tid >> 1) & 63)) * G4 + (tid >> 7) * RNN + n0 +
        (tid & 1) * 8;
    const float* csrc = c + (size_t)(m0 + (tid >> 2)) * RNN + n0 + (tid & 3) * 4;

#define STAGE(buf, k0) do {                                                    \
    __builtin_amdgcn_global_load_lds((const GAS unsigned int*)(a1src + (k0)),  \
        (LAS unsigned int*)&Abuf[buf][w * 512], 16, 0, 0);                     \
    __builtin_amdgcn_global_load_lds((const GAS unsigned int*)(a2src + (k0)),  \
        (LAS unsigned int*)&Abuf[buf][4096 + w * 512], 16, 0, 0);              \
    __builtin_amdgcn_global_load_lds((const GAS unsigned int*)(b1src + (k0)),  \
        (LAS unsigned int*)&Bbuf[buf][w * 512], 16, 0, 0);                     \
    __builtin_amdgcn_global_load_lds((const GAS unsigned int*)(b2src + (k0)),  \
        (LAS unsigned int*)&Bbuf[buf][4096 + w * 512], 16, 0, 0); } while (0)

    if (w < 4)
        __builtin_amdgcn_global_load_lds((const GAS unsigned int*)csrc,
            (LAS unsigned int*)&cld[w * 16][0], 16, 0, 0);
    __builtin_amdgcn_global_load_lds((const GAS unsigned int*)xsrc,
        (LAS unsigned int*)&xg[w * 512], 16, 0, 0);
    STAGE(0, 0); STAGE(1, 128);

    f32x4 acc[2] = {};
    #pragma unroll
    for (int it = 0; it < 8; ++it) {
        if (it <= 5) STAGE((it + 2) % 3, (it + 2) * 128);
        if (it <= 5)      asm volatile("s_waitcnt vmcnt(8)" ::: "memory");
        else if (it == 6) asm volatile("s_waitcnt vmcnt(4)" ::: "memory");
        else              asm volatile("s_waitcnt vmcnt(0)" ::: "memory");
        asm volatile("s_barrier" ::: "memory");
        __builtin_amdgcn_sched_barrier(0);
        const unsigned short* Ab = Abuf[it % 3];
        const unsigned short* Bb = Bbuf[it % 3];
        #pragma unroll
        for (int ks = 0; ks < 4; ++ks) {
            const int j = ((ks * 4 + q) ^ lr) * 8;   // swizzled 16B sub-chunk
            bf16x8 a0 = *(const bf16x8*)(Ab + (mh * 32 + lr) * 128 + j);
            bf16x8 a1 = *(const bf16x8*)(Ab + (mh * 32 + 16 + lr) * 128 + j);
            bf16x8 bv = *(const bf16x8*)(Bb + (g * 16 + lr) * 128 + j);
            acc[0] = __builtin_amdgcn_mfma_f32_16x16x32_bf16(a0, bv, acc[0], 0, 0, 0);
            acc[1] = __builtin_amdgcn_mfma_f32_16x16x32_bf16(a1, bv, acc[1], 0, 0, 0);
        }
        asm volatile("s_waitcnt lgkmcnt(0)" ::: "memory");
        __builtin_amdgcn_sched_barrier(0);
        asm volatile("s_barrier" ::: "memory");
    }

    // epilogue: gates = acc + xg (wave-exclusive (g, mh) rows)
    #pragma unroll
    for (int mi = 0; mi < 2; ++mi)
        #pragma unroll
        for (int r = 0; r < 4; ++r) {
            const int row = mh * 32 + mi * 16 + q * 4 + r;
            gates[g][row][lr] = acc[mi][r] +
                bf2f(xg[(g * 64 + row) * 16 + lr]);
        }
    __syncthreads();

    // LSTM tail: 1024 elements (64x16), 2 per thread; c from LDS prefetch
    #pragma unroll
    for (int q2 = 0; q2 < 2; ++q2) {
        const int e = tid + q2 * 512;
        const int row = e >> 4, col = e & 15;
        const int b = m0 + row, j = n0 + col;
        const float xi = gates[0][row][col];
        const float xf = gates[1][row][col];
        const float xgt = gates[2][row][col];
        const float xo = gates[3][row][col];
        const float si = fsig(xi);
        const float sf = fsig(xf);
        const float so = fsig(xo);
        const float cp = cld[row][col];
        const float cn = sf * cp + si * ftanh(xgt);
        const float hn = so * ftanh(cn);
        c[(size_t)b * RNN + j] = cn;
        h_next[(size_t)b * RNN + j] = f2bf(hn);
    }
#undef STAGE
}

// gate[b*50+t] = gatectx[b] + h_all[t+1][b]·w_gate[0:1024] ; one wave per row
__global__ void k_gate(const unsigned short* __restrict__ h,  // [12800][1024]
                       const float* __restrict__ wgate,
                       const float* __restrict__ gctx,
                       float* __restrict__ out1) {
    const int gw = (blockIdx.x * blockDim.x + threadIdx.x) >> 6;
    const int lane = threadIdx.x & 63;
    if (gw >= MROWS) return;
    const unsigned short* hr = h + (size_t)gw * RNN + lane * 16;
    const float* wr = wgate + lane * 16;
    float acc = 0.f;
    #pragma unroll
    for (int j = 0; j < 16; ++j) acc += bf2f(hr[j]) * wr[j];
    for (int off = 32; off; off >>= 1) acc += __shfl_down(acc, off);
    if (lane == 0) {
        const int t = gw >> 8, b = gw & 255;
        out1[b * TT + t] = acc + gctx[b];
    }
}

// ---------------- workspace layout (all offsets 1KB-aligned) ----------------
static const size_t OFF_WIH   = 0;                                    // 10.5 MB
static const size_t OFF_WHH   = OFF_WIH   + (size_t)G4 * INDIM * 2;   // 8 MB
static const size_t OFF_WPH   = OFF_WHH   + (size_t)G4 * RNN * 2;     // 2.6 MB
static const size_t OFF_FRM   = OFF_WPH   + (size_t)INDIM * RNN * 2;  // 32.8 MB
static const size_t OFF_XPROJ = OFF_FRM   + (size_t)MROWS * INDIM * 2;// 104.9 MB
static const size_t OFF_HALL  = OFF_XPROJ + (size_t)MROWS * G4 * 2;   // 26.7 MB
static const size_t OFF_C     = OFF_HALL  + (size_t)(TT + 1) * BB * RNN * 2;
static const size_t OFF_CTX   = OFF_C     + (size_t)BB * RNN * 4;
static const size_t OFF_GCTX  = OFF_CTX   + (size_t)BB * INDIM * 4;

extern "C" void kernel_launch(void* const* d_in, const int* in_sizes, int n_in,
                              void* d_out, int out_size, void* d_ws, size_t ws_size,
                              hipStream_t stream) {
    const float* context = (const float*)d_in[0];
    const float* target  = (const float*)d_in[1];
    const float* W_ih    = (const float*)d_in[2];
    const float* b_ih    = (const float*)d_in[3];
    const float* W_hh    = (const float*)d_in[4];
    const float* b_hh    = (const float*)d_in[5];
    const float* W_proj  = (const float*)d_in[6];
    const float* b_proj  = (const float*)d_in[7];
    const float* W_gate  = (const float*)d_in[8];
    const float* b_gate  = (const float*)d_in[9];
    float* out = (float*)d_out;
    char* ws = (char*)d_ws;

    unsigned short* wih_bf  = (unsigned short*)(ws + OFF_WIH);
    unsigned short* whh_bf  = (unsigned short*)(ws + OFF_WHH);
    unsigned short* wph_bf  = (unsigned short*)(ws + OFF_WPH);
    unsigned short* frames  = (unsigned short*)(ws + OFF_FRM);
    unsigned short* xproj   = (unsigned short*)(ws + OFF_XPROJ);
    unsigned short* h_all   = (unsigned short*)(ws + OFF_HALL);
    float*          c_buf   = (float*)(ws + OFF_C);
    float*          ctxproj = (float*)(ws + OFF_CTX);
    float*          gctx    = (float*)(ws + OFF_GCTX);

    // per-call init (harness does not re-zero ws between replays)
    hipMemsetAsync(h_all, 0, (size_t)BB * RNN * 2, stream);   // h0 slot
    hipMemsetAsync(c_buf, 0, (size_t)BB * RNN * 4, stream);   // c0

    k_f32_to_bf16<<<2048, 256, 0, stream>>>(W_ih, wih_bf, G4 * INDIM);
    k_f32_to_bf16<<<2048, 256, 0, stream>>>(W_hh, whh_bf, G4 * RNN);
    k_conv_wph<<<2048, 256, 0, stream>>>(W_proj, wph_bf);
    k_frames<<<2048, 256, 0, stream>>>(target, frames);
    k_ctxproj<<<(BB * INDIM + 255) / 256, 256, 0, stream>>>(context, W_proj,
                                                            b_proj, ctxproj);
    k_gatectx<<<1, 256, 0, stream>>>(context, W_gate, b_gate, gctx);

    k_gemm_xproj<<<dim3(G4 / 128, MROWS / 128), 512, 0, stream>>>(
        frames, wih_bf, b_ih, b_hh, xproj);

    for (int t = 0; t < TT; ++t) {
        k_step<<<dim3(64, 4), 512, 0, stream>>>(
            whh_bf, xproj + (size_t)t * BB * G4,
            h_all + (size_t)t * BB * RNN,
            h_all + (size_t)(t + 1) * BB * RNN, c_buf);
    }

    k_gemm_mel<<<dim3(INDIM / 128, MROWS / 128), 512, 0, stream>>>(
        h_all + (size_t)BB * RNN, wph_bf, ctxproj, out);
    k_gate<<<MROWS / 4, 256, 0, stream>>>(h_all + (size_t)BB * RNN, W_gate,
                                          gctx, out + (size_t)BB * NMEL * TMEL);
}